// Round 1
// baseline (321.501 us; speedup 1.0000x reference)
//
#include <hip/hip_runtime.h>

#define B_ 4
#define C_ 256
#define S_ 2304
#define NH_ 8
#define HD_ 32
#define QSCALE 0.17677669529663687f

typedef __attribute__((ext_vector_type(8))) short s16x8;
typedef __attribute__((ext_vector_type(8))) __bf16 b16x8;
typedef __attribute__((ext_vector_type(4))) float f32x4;

static __device__ __forceinline__ f32x4 mfma_bf16(s16x8 a, s16x8 b, f32x4 c) {
  return __builtin_amdgcn_mfma_f32_16x16x32_bf16(
      __builtin_bit_cast(b16x8, a), __builtin_bit_cast(b16x8, b), c, 0, 0, 0);
}

// f32 -> bf16 round-to-nearest-even, pure bit ops (no __hip_bfloat16 API dependence)
static __device__ __forceinline__ unsigned short f2bf(float f) {
  unsigned u = __builtin_bit_cast(unsigned, f);
  u = u + 0x7FFFu + ((u >> 16) & 1u);
  return (unsigned short)(u >> 16);
}

// ---------------- K1: QKV projections ----------------
// wave = (proj p, i-tile, token-tile). q[i][t] = sum_c W[i][c] * src[b][c][s0+t] + bias[i]
__global__ __launch_bounds__(256) void k_qkv(
    const float* __restrict__ x, const float* __restrict__ ctx,
    const float* __restrict__ Wq, const float* __restrict__ bq,
    const float* __restrict__ Wk, const float* __restrict__ bk,
    const float* __restrict__ Wv, const float* __restrict__ bv,
    unsigned short* __restrict__ Q, unsigned short* __restrict__ Kd,
    unsigned short* __restrict__ Vt) {
  const int w = blockIdx.x * 4 + (threadIdx.x >> 6);
  const int lane = threadIdx.x & 63;
  const int col = lane & 15, g = lane >> 4;
  const int p = w / 9216;           // 0=Q 1=K 2=V
  const int r0 = w % 9216;
  const int it = r0 & 15;           // i-tile fastest: 4 waves of a block share token tile
  const int tt = r0 >> 4;
  const int b = tt / 144;
  const int s0 = (tt % 144) * 16;
  const int i0 = it * 16;
  const float* W    = p == 0 ? Wq : (p == 1 ? Wk : Wv);
  const float* bias = p == 0 ? bq : (p == 1 ? bk : bv);
  const float* src  = p == 0 ? x : ctx;

  f32x4 acc = {0.f, 0.f, 0.f, 0.f};
  const float* wrow = W + (i0 + col) * C_;
  const float* scol = src + b * C_ * S_ + s0 + col;
  for (int kk = 0; kk < 8; ++kk) {
    const int c0 = kk * 32 + g * 8;
    f32x4 a0 = *(const f32x4*)(wrow + c0);
    f32x4 a1 = *(const f32x4*)(wrow + c0 + 4);
    s16x8 af, bf;
#pragma unroll
    for (int i = 0; i < 4; ++i) { af[i] = (short)f2bf(a0[i]); af[4 + i] = (short)f2bf(a1[i]); }
#pragma unroll
    for (int i = 0; i < 8; ++i) bf[i] = (short)f2bf(scol[(c0 + i) * S_]);
    acc = mfma_bf16(af, bf, acc);
  }
#pragma unroll
  for (int r = 0; r < 4; ++r) {
    const int i = i0 + g * 4 + r;      // output channel
    float val = acc[r] + bias[i];
    const int h = i >> 5, d = i & 31;
    if (p == 0) {
      val *= QSCALE;
      Q[((b * NH_ + h) * S_ + s0 + col) * HD_ + d] = f2bf(val);
    } else if (p == 1) {
      Kd[((b * NH_ + h) * S_ + s0 + col) * HD_ + d] = f2bf(val);
    } else {
      Vt[((b * NH_ + h) * HD_ + d) * S_ + s0 + col] = f2bf(val);  // V transposed [d][s]
    }
  }
}

// ---------------- K2: flash attention ----------------
// wave = (b,h, 16-query tile); streams 32 keys/iter.
// scores^T = mfma(Kfrag, Qfrag) with permuted key rows so P regs == PV A-fragment.
__global__ __launch_bounds__(256) void k_attn(
    const unsigned short* __restrict__ Q, const unsigned short* __restrict__ Kd,
    const unsigned short* __restrict__ Vt, unsigned short* __restrict__ att) {
  const int w = blockIdx.x * 4 + (threadIdx.x >> 6);
  const int lane = threadIdx.x & 63;
  const int col = lane & 15, g = lane >> 4;
  const int bh = w / 144;
  const int qt = w % 144;
  const int b = bh >> 3, h = bh & 7;
  const int s0 = qt * 16;
  const unsigned short* Qb = Q + (size_t)bh * S_ * HD_;
  const unsigned short* Kb = Kd + (size_t)bh * S_ * HD_;
  const unsigned short* Vb = Vt + (size_t)bh * HD_ * S_;

  const s16x8 qf = *(const s16x8*)(Qb + (s0 + col) * HD_ + g * 8);
  // matrix row (=col) holds key kA (tile A) / kA+4 (tile B):
  const int kA = ((col >> 2) * 8) + (col & 3);

  f32x4 acc0 = {0, 0, 0, 0}, acc1 = {0, 0, 0, 0};
  const f32x4 zero = {0, 0, 0, 0};
  float m_run = -1e30f, l_run = 0.f;

  for (int k0 = 0; k0 < S_; k0 += 32) {
    s16x8 ka = *(const s16x8*)(Kb + (k0 + kA) * HD_ + g * 8);
    s16x8 kb = *(const s16x8*)(Kb + (k0 + kA + 4) * HD_ + g * 8);
    f32x4 sA = mfma_bf16(ka, qf, zero);  // sA[r] = score[key=8g+r  ][q=col]
    f32x4 sB = mfma_bf16(kb, qf, zero);  // sB[r] = score[key=8g+4+r][q=col]

    float m_t = fmaxf(fmaxf(fmaxf(sA[0], sA[1]), fmaxf(sA[2], sA[3])),
                      fmaxf(fmaxf(sB[0], sB[1]), fmaxf(sB[2], sB[3])));
    m_t = fmaxf(m_t, __shfl_xor(m_t, 16));
    m_t = fmaxf(m_t, __shfl_xor(m_t, 32));
    const float m_new = fmaxf(m_run, m_t);
    const float factor = __expf(m_run - m_new);  // first iter: exp(-1e30-x)=0
    f32x4 pA, pB;
#pragma unroll
    for (int r = 0; r < 4; ++r) { pA[r] = __expf(sA[r] - m_new); pB[r] = __expf(sB[r] - m_new); }
    float l_t = pA[0] + pA[1] + pA[2] + pA[3] + pB[0] + pB[1] + pB[2] + pB[3];
    l_t += __shfl_xor(l_t, 16);
    l_t += __shfl_xor(l_t, 32);
    l_run = l_run * factor + l_t;
    m_run = m_new;
#pragma unroll
    for (int r = 0; r < 4; ++r) {          // acc rows are q=g*4+r; factor lives in lane q
      const float fr = __shfl(factor, g * 4 + r);
      acc0[r] *= fr; acc1[r] *= fr;
    }
    s16x8 pf;
#pragma unroll
    for (int r = 0; r < 4; ++r) { pf[r] = (short)f2bf(pA[r]); pf[4 + r] = (short)f2bf(pB[r]); }
    s16x8 v0 = *(const s16x8*)(Vb + col * S_ + k0 + g * 8);
    s16x8 v1 = *(const s16x8*)(Vb + (16 + col) * S_ + k0 + g * 8);
    acc0 = mfma_bf16(pf, v0, acc0);  // attended[q][d=col]
    acc1 = mfma_bf16(pf, v1, acc1);  // attended[q][d=16+col]
  }
#pragma unroll
  for (int r = 0; r < 4; ++r) {
    const int q = g * 4 + r;
    const float lr = __shfl(l_run, q);
    const float inv = 1.f / lr;
    const size_t base = ((size_t)b * S_ + s0 + q) * C_ + h * HD_;
    att[base + col] = f2bf(acc0[r] * inv);
    att[base + 16 + col] = f2bf(acc1[r] * inv);
  }
}

// ---------------- K3: output projection + residual -> y (f32, [b][s][c]) ----------------
__global__ __launch_bounds__(256) void k_oproj(
    const unsigned short* __restrict__ att, const float* __restrict__ Wo,
    const float* __restrict__ bo, const float* __restrict__ x, float* __restrict__ y) {
  const int w = blockIdx.x * 4 + (threadIdx.x >> 6);
  const int lane = threadIdx.x & 63;
  const int col = lane & 15, g = lane >> 4;
  const int it = w & 15;
  const int tt = w >> 4;
  const int b = tt / 144;
  const int s0 = (tt % 144) * 16;
  const int i0 = it * 16;
  f32x4 acc = {0, 0, 0, 0};
  const float* wrow = Wo + (i0 + col) * C_;
  const unsigned short* arow = att + ((size_t)b * S_ + s0 + col) * C_;
  for (int kk = 0; kk < 8; ++kk) {
    const int c0 = kk * 32 + g * 8;
    f32x4 a0 = *(const f32x4*)(wrow + c0);
    f32x4 a1 = *(const f32x4*)(wrow + c0 + 4);
    s16x8 af;
#pragma unroll
    for (int i = 0; i < 4; ++i) { af[i] = (short)f2bf(a0[i]); af[4 + i] = (short)f2bf(a1[i]); }
    s16x8 bfr = *(const s16x8*)(arow + c0);
    acc = mfma_bf16(af, bfr, acc);
  }
#pragma unroll
  for (int r = 0; r < 4; ++r) {
    const int i = i0 + g * 4 + r;
    const float val = acc[r] + bo[i] + x[((size_t)b * C_ + i) * S_ + s0 + col];
    y[((size_t)b * S_ + s0 + col) * C_ + i] = val;
  }
}

// ---------------- K4: LayerNorm over C + transpose to (B,C,S) ----------------
__global__ __launch_bounds__(256) void k_lnorm(
    const float* __restrict__ y, const float* __restrict__ lnw,
    const float* __restrict__ lnb, float* __restrict__ out) {
  __shared__ float ly[32 * 257];
  __shared__ float lmu[32], lrs[32];
  const int b = blockIdx.x / 72;
  const int s0 = (blockIdx.x % 72) * 32;
  const int tid = threadIdx.x;
  const float* ysrc = y + ((size_t)b * S_ + s0) * C_;
  for (int e = tid; e < 32 * C_; e += 256) {
    const int t = e >> 8, c = e & 255;
    ly[t * 257 + c] = ysrc[e];
  }
  __syncthreads();
  {
    const int t = tid >> 3;
    const int j0 = (tid & 7) * 32;
    float s = 0.f, s2 = 0.f;
#pragma unroll
    for (int j = 0; j < 32; ++j) { const float v = ly[t * 257 + j0 + j]; s += v; s2 += v * v; }
    s += __shfl_xor(s, 1); s2 += __shfl_xor(s2, 1);
    s += __shfl_xor(s, 2); s2 += __shfl_xor(s2, 2);
    s += __shfl_xor(s, 4); s2 += __shfl_xor(s2, 4);
    if ((tid & 7) == 0) {
      const float mu = s * (1.f / 256.f);
      const float var = s2 * (1.f / 256.f) - mu * mu;
      lmu[t] = mu;
      lrs[t] = rsqrtf(var + 1e-5f);
    }
  }
  __syncthreads();
  float* od = out + (size_t)b * C_ * S_ + s0;
  for (int e = tid; e < 32 * C_; e += 256) {
    const int c = e >> 5, t = e & 31;
    const float v = (ly[t * 257 + c] - lmu[t]) * lrs[t] * lnw[c] + lnb[c];
    od[(size_t)c * S_ + t] = v;
  }
}

extern "C" void kernel_launch(void* const* d_in, const int* in_sizes, int n_in,
                              void* d_out, int out_size, void* d_ws, size_t ws_size,
                              hipStream_t stream) {
  const float* x   = (const float*)d_in[0];
  const float* ctx = (const float*)d_in[1];
  const float* Wq  = (const float*)d_in[2];
  const float* bq  = (const float*)d_in[3];
  const float* Wk  = (const float*)d_in[4];
  const float* bk  = (const float*)d_in[5];
  const float* Wv  = (const float*)d_in[6];
  const float* bv  = (const float*)d_in[7];
  const float* Wo  = (const float*)d_in[8];
  const float* bo  = (const float*)d_in[9];
  const float* lnw = (const float*)d_in[10];
  const float* lnb = (const float*)d_in[11];
  float* out = (float*)d_out;

  char* ws = (char*)d_ws;
  unsigned short* Q   = (unsigned short*)(ws);              // 4,718,592 B
  unsigned short* Kd  = (unsigned short*)(ws + 4718592);    // 4,718,592 B
  unsigned short* Vt  = (unsigned short*)(ws + 9437184);    // 4,718,592 B
  unsigned short* att = (unsigned short*)(ws + 14155776);   // 4,718,592 B
  float* y            = (float*)(ws + 18874368);            // 9,437,184 B

  k_qkv  <<<6912, 256, 0, stream>>>(x, ctx, Wq, bq, Wk, bk, Wv, bv, Q, Kd, Vt);
  k_attn <<<1152, 256, 0, stream>>>(Q, Kd, Vt, att);
  k_oproj<<<2304, 256, 0, stream>>>(att, Wo, bo, x, y);
  k_lnorm<<< 288, 256, 0, stream>>>(y, lnw, lnb, out);
}

// Round 2
// 301.506 us; speedup vs baseline: 1.0663x; 1.0663x over previous
//
#include <hip/hip_runtime.h>

#define B_ 4
#define C_ 256
#define S_ 2304
#define NH_ 8
#define HD_ 32
// (1/sqrt(32)) * log2(e) folded into Q so softmax is exp2
#define QS_L2E (0.17677669529663687f * 1.4426950408889634f)

typedef __attribute__((ext_vector_type(8))) __bf16 b16x8;
typedef __attribute__((ext_vector_type(4))) __bf16 b16x4;
typedef __attribute__((ext_vector_type(4))) float f32x4;

static __device__ __forceinline__ f32x4 mfma_bf16(b16x8 a, b16x8 b, f32x4 c) {
  return __builtin_amdgcn_mfma_f32_16x16x32_bf16(a, b, c, 0, 0, 0);
}

// ---------------- K0: convert/transpose x,ctx -> bf16 [b][s][c]; W -> bf16 ----------------
__global__ __launch_bounds__(256) void k_cvt(
    const float* __restrict__ x, const float* __restrict__ ctx,
    const float* __restrict__ Wq, const float* __restrict__ Wk,
    const float* __restrict__ Wv, const float* __restrict__ Wo,
    __bf16* __restrict__ xT, __bf16* __restrict__ cT,
    __bf16* __restrict__ Wb, __bf16* __restrict__ Wob) {
  const int bid = blockIdx.x, t = threadIdx.x;
  if (bid < 4608) {
    __shared__ float tile[32][33];
    const int s = bid / 2304;
    int r = bid % 2304;
    const int b = r / 576; r %= 576;
    const int ct = r / 72, st = r % 72;
    const float* src = (s == 0 ? x : ctx) + ((size_t)b * C_ + ct * 32) * S_ + st * 32;
    const int tr = t >> 3, tc = (t & 7) * 4;
    f32x4 v = *(const f32x4*)(src + (size_t)tr * S_ + tc);
    tile[tr][tc] = v[0]; tile[tr][tc + 1] = v[1];
    tile[tr][tc + 2] = v[2]; tile[tr][tc + 3] = v[3];
    __syncthreads();
    __bf16* dst = (s == 0 ? xT : cT) + ((size_t)b * S_ + st * 32 + tr) * C_ + ct * 32 + tc;
    b16x4 o;
#pragma unroll
    for (int j = 0; j < 4; ++j) o[j] = (__bf16)tile[tc + j][tr];
    *(b16x4*)dst = o;
  } else {
    const int wi = bid - 4608;              // 0..255
    const int m = wi >> 6, chunk = wi & 63;
    const float* Wsrc = m == 0 ? Wq : (m == 1 ? Wk : (m == 2 ? Wv : Wo));
    __bf16* Wdst = (m < 3) ? (Wb + m * 65536) : Wob;
    const int e0 = chunk * 1024 + t * 4;
    f32x4 v = *(const f32x4*)(Wsrc + e0);
    b16x4 o;
#pragma unroll
    for (int j = 0; j < 4; ++j) o[j] = (__bf16)v[j];
    *(b16x4*)(Wdst + e0) = o;
  }
}

// ---------------- K1: QKV projections (bf16 in, bf16 out) ----------------
// block = (p, b, token-tile); 4 waves = 4 x 64 output channels
__global__ __launch_bounds__(256) void k_qkv(
    const __bf16* __restrict__ xT, const __bf16* __restrict__ cT,
    const __bf16* __restrict__ Wb,
    const float* __restrict__ bq, const float* __restrict__ bk, const float* __restrict__ bv,
    __bf16* __restrict__ Q, __bf16* __restrict__ Kd, __bf16* __restrict__ Vt) {
  const int iblk = threadIdx.x >> 6;
  const int lane = threadIdx.x & 63;
  const int col = lane & 15, g = lane >> 4;
  int r = blockIdx.x;                        // 1728 = 3 * 4 * 144
  const int p = r / 576; r %= 576;
  const int b = r / 144;
  const int s0 = (r % 144) * 16;
  const __bf16* src = (p == 0 ? xT : cT) + (size_t)b * S_ * C_;
  const __bf16* W = Wb + p * 65536;
  const float* bias = p == 0 ? bq : (p == 1 ? bk : bv);
  const int i0 = iblk * 64;

  f32x4 acc[4] = {};
  const __bf16* brow = src + (size_t)(s0 + col) * C_ + g * 8;
  const __bf16* arow = W + (size_t)(i0 + col) * C_ + g * 8;
  for (int kk = 0; kk < 8; ++kk) {
    b16x8 bf = *(const b16x8*)(brow + kk * 32);
#pragma unroll
    for (int j = 0; j < 4; ++j) {
      b16x8 af = *(const b16x8*)(arow + (size_t)j * 16 * C_ + kk * 32);
      acc[j] = mfma_bf16(af, bf, acc[j]);
    }
  }
#pragma unroll
  for (int j = 0; j < 4; ++j) {
#pragma unroll
    for (int rr = 0; rr < 4; ++rr) {
      const int i = i0 + j * 16 + g * 4 + rr;
      float val = acc[j][rr] + bias[i];
      const int h = i >> 5, d = i & 31;
      const size_t bh = (size_t)b * NH_ + h;
      if (p == 0)      Q[(bh * S_ + s0 + col) * HD_ + d] = (__bf16)(val * QS_L2E);
      else if (p == 1) Kd[(bh * S_ + s0 + col) * HD_ + d] = (__bf16)val;
      else             Vt[(bh * HD_ + d) * S_ + s0 + col] = (__bf16)val;  // V transposed [d][s]
    }
  }
}

// ---------------- K2: flash attention, no-max softmax (scores bounded ~|2.5| in log2 domain) ----------------
__global__ __launch_bounds__(256) void k_attn(
    const __bf16* __restrict__ Q, const __bf16* __restrict__ Kd,
    const __bf16* __restrict__ Vt, __bf16* __restrict__ att) {
  int bid = blockIdx.x;
  bid = (bid & 7) * 144 + (bid >> 3);   // XCD swizzle: 144 logical blocks (4 bh) per XCD
  const int w = bid * 4 + (threadIdx.x >> 6);
  const int lane = threadIdx.x & 63;
  const int col = lane & 15, g = lane >> 4;
  const int bh = w / 144;
  const int qt = w % 144;
  const int b = bh >> 3, h = bh & 7;
  const int s0 = qt * 16;
  const __bf16* Qb = Q + (size_t)bh * S_ * HD_;
  const __bf16* Kb = Kd + (size_t)bh * S_ * HD_;
  const __bf16* Vb = Vt + (size_t)bh * HD_ * S_;

  const b16x8 qf = *(const b16x8*)(Qb + (s0 + col) * HD_ + g * 8);
  // permuted key->row mapping so exp'd score regs match the PV A-fragment layout
  const int kA = ((col >> 2) * 8) + (col & 3);

  f32x4 acc0 = {}, acc1 = {};
  const f32x4 zero = {};
  float lsum = 0.f;

  for (int k0 = 0; k0 < S_; k0 += 32) {
    b16x8 ka = *(const b16x8*)(Kb + (size_t)(k0 + kA) * HD_ + g * 8);
    b16x8 kb = *(const b16x8*)(Kb + (size_t)(k0 + kA + 4) * HD_ + g * 8);
    f32x4 sA = mfma_bf16(ka, qf, zero);  // sA[r] = score[key][q=col]
    f32x4 sB = mfma_bf16(kb, qf, zero);
    f32x4 pA, pB;
#pragma unroll
    for (int rr = 0; rr < 4; ++rr) {
      pA[rr] = __builtin_exp2f(sA[rr]);
      pB[rr] = __builtin_exp2f(sB[rr]);
    }
    lsum += ((pA[0] + pA[1]) + (pA[2] + pA[3])) + ((pB[0] + pB[1]) + (pB[2] + pB[3]));
    b16x8 pf;
#pragma unroll
    for (int rr = 0; rr < 4; ++rr) { pf[rr] = (__bf16)pA[rr]; pf[4 + rr] = (__bf16)pB[rr]; }
    b16x8 v0 = *(const b16x8*)(Vb + (size_t)col * S_ + k0 + g * 8);
    b16x8 v1 = *(const b16x8*)(Vb + (size_t)(16 + col) * S_ + k0 + g * 8);
    acc0 = mfma_bf16(pf, v0, acc0);  // attended[q][d=col]
    acc1 = mfma_bf16(pf, v1, acc1);  // attended[q][d=16+col]
  }
  lsum += __shfl_xor(lsum, 16);
  lsum += __shfl_xor(lsum, 32);
#pragma unroll
  for (int rr = 0; rr < 4; ++rr) {
    const int q = g * 4 + rr;
    const float inv = 1.f / __shfl(lsum, q);
    const size_t base = ((size_t)b * S_ + s0 + q) * C_ + h * HD_;
    att[base + col] = (__bf16)(acc0[rr] * inv);
    att[base + 16 + col] = (__bf16)(acc1[rr] * inv);
  }
}

// ---------------- K3: output projection + residual -> y (f32, [b][s][c]) ----------------
__global__ __launch_bounds__(256) void k_oproj(
    const __bf16* __restrict__ att, const __bf16* __restrict__ Wob,
    const float* __restrict__ bo, const float* __restrict__ x, float* __restrict__ y) {
  const int iblk = threadIdx.x >> 6;
  const int lane = threadIdx.x & 63;
  const int col = lane & 15, g = lane >> 4;
  int r = blockIdx.x;                        // 576 = 4 * 144
  const int b = r / 144;
  const int s0 = (r % 144) * 16;
  const int i0 = iblk * 64;
  f32x4 acc[4] = {};
  const __bf16* arow = att + ((size_t)b * S_ + s0 + col) * C_ + g * 8;
  const __bf16* wrow = Wob + (size_t)(i0 + col) * C_ + g * 8;
  for (int kk = 0; kk < 8; ++kk) {
    b16x8 bfr = *(const b16x8*)(arow + kk * 32);
#pragma unroll
    for (int j = 0; j < 4; ++j) {
      b16x8 af = *(const b16x8*)(wrow + (size_t)j * 16 * C_ + kk * 32);
      acc[j] = mfma_bf16(af, bfr, acc[j]);
    }
  }
#pragma unroll
  for (int j = 0; j < 4; ++j) {
#pragma unroll
    for (int rr = 0; rr < 4; ++rr) {
      const int i = i0 + j * 16 + g * 4 + rr;
      const float val = acc[j][rr] + bo[i] + x[((size_t)b * C_ + i) * S_ + s0 + col];
      y[((size_t)b * S_ + s0 + col) * C_ + i] = val;
    }
  }
}

// ---------------- K4: LayerNorm over C + transpose to (B,C,S) ----------------
__global__ __launch_bounds__(256) void k_lnorm(
    const float* __restrict__ y, const float* __restrict__ lnw,
    const float* __restrict__ lnb, float* __restrict__ out) {
  __shared__ float ly[32 * 257];
  __shared__ float lmu[32], lrs[32];
  const int b = blockIdx.x / 72;
  const int s0 = (blockIdx.x % 72) * 32;
  const int tid = threadIdx.x;
  const float* ysrc = y + ((size_t)b * S_ + s0) * C_;
  for (int e = tid; e < 32 * C_; e += 256) {
    const int t = e >> 8, c = e & 255;
    ly[t * 257 + c] = ysrc[e];
  }
  __syncthreads();
  {
    const int t = tid >> 3;
    const int j0 = (tid & 7) * 32;
    float s = 0.f, s2 = 0.f;
#pragma unroll
    for (int j = 0; j < 32; ++j) { const float v = ly[t * 257 + j0 + j]; s += v; s2 += v * v; }
    s += __shfl_xor(s, 1); s2 += __shfl_xor(s2, 1);
    s += __shfl_xor(s, 2); s2 += __shfl_xor(s2, 2);
    s += __shfl_xor(s, 4); s2 += __shfl_xor(s2, 4);
    if ((tid & 7) == 0) {
      const float mu = s * (1.f / 256.f);
      const float var = s2 * (1.f / 256.f) - mu * mu;
      lmu[t] = mu;
      lrs[t] = rsqrtf(var + 1e-5f);
    }
  }
  __syncthreads();
  float* od = out + (size_t)b * C_ * S_ + s0;
  for (int e = tid; e < 32 * C_; e += 256) {
    const int c = e >> 5, t = e & 31;
    const float v = (ly[t * 257 + c] - lmu[t]) * lrs[t] * lnw[c] + lnb[c];
    od[(size_t)c * S_ + t] = v;
  }
}

extern "C" void kernel_launch(void* const* d_in, const int* in_sizes, int n_in,
                              void* d_out, int out_size, void* d_ws, size_t ws_size,
                              hipStream_t stream) {
  const float* x   = (const float*)d_in[0];
  const float* ctx = (const float*)d_in[1];
  const float* Wq  = (const float*)d_in[2];
  const float* bq  = (const float*)d_in[3];
  const float* Wk  = (const float*)d_in[4];
  const float* bk  = (const float*)d_in[5];
  const float* Wv  = (const float*)d_in[6];
  const float* bv  = (const float*)d_in[7];
  const float* Wo  = (const float*)d_in[8];
  const float* bo  = (const float*)d_in[9];
  const float* lnw = (const float*)d_in[10];
  const float* lnb = (const float*)d_in[11];
  float* out = (float*)d_out;

  char* ws = (char*)d_ws;
  __bf16* xT  = (__bf16*)(ws);               // 4,718,592 B (dead after k_qkv)
  __bf16* cT  = (__bf16*)(ws + 4718592);     // 4,718,592 B (dead after k_qkv)
  __bf16* Wb  = (__bf16*)(ws + 9437184);     //   393,216 B (Wq,Wk,Wv bf16)
  __bf16* Wob = (__bf16*)(ws + 9830400);     //   131,072 B
  __bf16* Q   = (__bf16*)(ws + 9961472);     // 4,718,592 B
  __bf16* Kd  = (__bf16*)(ws + 14680064);    // 4,718,592 B
  __bf16* Vt  = (__bf16*)(ws + 19398656);    // 4,718,592 B
  __bf16* att = (__bf16*)(ws + 24117248);    // 4,718,592 B
  float*  y   = (float*)(ws);                // 9,437,184 B — reuses dead xT+cT

  k_cvt  <<<4864, 256, 0, stream>>>(x, ctx, Wq, Wk, Wv, Wo, xT, cT, Wb, Wob);
  k_qkv  <<<1728, 256, 0, stream>>>(xT, cT, Wb, bq, bk, bv, Q, Kd, Vt);
  k_attn <<<1152, 256, 0, stream>>>(Q, Kd, Vt, att);
  k_oproj<<< 576, 256, 0, stream>>>(att, Wob, bo, x, y);
  k_lnorm<<< 288, 256, 0, stream>>>(y, lnw, lnb, out);
}

// Round 3
// 287.364 us; speedup vs baseline: 1.1188x; 1.0492x over previous
//
#include <hip/hip_runtime.h>

#define B_ 4
#define C_ 256
#define S_ 2304
#define NH_ 8
#define HD_ 32
// (1/sqrt(32)) * log2(e) folded into Q so softmax is exp2
#define QS_L2E (0.17677669529663687f * 1.4426950408889634f)

typedef __attribute__((ext_vector_type(8))) __bf16 b16x8;
typedef __attribute__((ext_vector_type(4))) __bf16 b16x4;
typedef __attribute__((ext_vector_type(4))) float f32x4;

static __device__ __forceinline__ f32x4 mfma_bf16(b16x8 a, b16x8 b, f32x4 c) {
  return __builtin_amdgcn_mfma_f32_16x16x32_bf16(a, b, c, 0, 0, 0);
}

// ---------------- K0: convert/transpose x,ctx -> bf16 [b][s][c]; W -> bf16 ----------------
__global__ __launch_bounds__(256) void k_cvt(
    const float* __restrict__ x, const float* __restrict__ ctx,
    const float* __restrict__ Wq, const float* __restrict__ Wk,
    const float* __restrict__ Wv, const float* __restrict__ Wo,
    __bf16* __restrict__ xT, __bf16* __restrict__ cT,
    __bf16* __restrict__ Wb, __bf16* __restrict__ Wob) {
  const int bid = blockIdx.x, t = threadIdx.x;
  if (bid < 4608) {
    __shared__ float tile[32][33];
    const int s = bid / 2304;
    int r = bid % 2304;
    const int b = r / 576; r %= 576;
    const int ct = r / 72, st = r % 72;
    const float* src = (s == 0 ? x : ctx) + ((size_t)b * C_ + ct * 32) * S_ + st * 32;
    const int tr = t >> 3, tc = (t & 7) * 4;
    f32x4 v = *(const f32x4*)(src + (size_t)tr * S_ + tc);
    tile[tr][tc] = v[0]; tile[tr][tc + 1] = v[1];
    tile[tr][tc + 2] = v[2]; tile[tr][tc + 3] = v[3];
    __syncthreads();
    __bf16* dst = (s == 0 ? xT : cT) + ((size_t)b * S_ + st * 32 + tr) * C_ + ct * 32 + tc;
    b16x4 o;
#pragma unroll
    for (int j = 0; j < 4; ++j) o[j] = (__bf16)tile[tc + j][tr];
    *(b16x4*)dst = o;
  } else {
    const int wi = bid - 4608;              // 0..255
    const int m = wi >> 6, chunk = wi & 63;
    const float* Wsrc = m == 0 ? Wq : (m == 1 ? Wk : (m == 2 ? Wv : Wo));
    __bf16* Wdst = (m < 3) ? (Wb + m * 65536) : Wob;
    const int e0 = chunk * 1024 + t * 4;
    f32x4 v = *(const f32x4*)(Wsrc + e0);
    b16x4 o;
#pragma unroll
    for (int j = 0; j < 4; ++j) o[j] = (__bf16)v[j];
    *(b16x4*)(Wdst + e0) = o;
  }
}

// ---------------- K1: QKV projections (bf16 in, bf16 out) ----------------
__global__ __launch_bounds__(256) void k_qkv(
    const __bf16* __restrict__ xT, const __bf16* __restrict__ cT,
    const __bf16* __restrict__ Wb,
    const float* __restrict__ bq, const float* __restrict__ bk, const float* __restrict__ bv,
    __bf16* __restrict__ Q, __bf16* __restrict__ Kd, __bf16* __restrict__ Vt) {
  const int iblk = threadIdx.x >> 6;
  const int lane = threadIdx.x & 63;
  const int col = lane & 15, g = lane >> 4;
  int r = blockIdx.x;                        // 1728 = 3 * 4 * 144
  const int p = r / 576; r %= 576;
  const int b = r / 144;
  const int s0 = (r % 144) * 16;
  const __bf16* src = (p == 0 ? xT : cT) + (size_t)b * S_ * C_;
  const __bf16* W = Wb + p * 65536;
  const float* bias = p == 0 ? bq : (p == 1 ? bk : bv);
  const int i0 = iblk * 64;

  f32x4 acc[4] = {};
  const __bf16* brow = src + (size_t)(s0 + col) * C_ + g * 8;
  const __bf16* arow = W + (size_t)(i0 + col) * C_ + g * 8;
#pragma unroll 2
  for (int kk = 0; kk < 8; ++kk) {
    b16x8 bf = *(const b16x8*)(brow + kk * 32);
#pragma unroll
    for (int j = 0; j < 4; ++j) {
      b16x8 af = *(const b16x8*)(arow + (size_t)j * 16 * C_ + kk * 32);
      acc[j] = mfma_bf16(af, bf, acc[j]);
    }
  }
#pragma unroll
  for (int j = 0; j < 4; ++j) {
#pragma unroll
    for (int rr = 0; rr < 4; ++rr) {
      const int i = i0 + j * 16 + g * 4 + rr;
      float val = acc[j][rr] + bias[i];
      const int h = i >> 5, d = i & 31;
      const size_t bh = (size_t)b * NH_ + h;
      if (p == 0)      Q[(bh * S_ + s0 + col) * HD_ + d] = (__bf16)(val * QS_L2E);
      else if (p == 1) Kd[(bh * S_ + s0 + col) * HD_ + d] = (__bf16)val;
      else             Vt[(bh * HD_ + d) * S_ + s0 + col] = (__bf16)val;  // V transposed [d][s]
    }
  }
}

// ---------------- K2: flash attention, split-K x2, software-pipelined ----------------
// block = 4 waves = 2 q-tiles x 2 key-halves; max-free softmax so partials add.
__global__ __launch_bounds__(256, 6) void k_attn(
    const __bf16* __restrict__ Q, const __bf16* __restrict__ Kd,
    const __bf16* __restrict__ Vt, __bf16* __restrict__ att) {
  __shared__ float mrg[2][528];  // [qt_local]: acc [d=32][q=16] + lsum[16]
  int bid = blockIdx.x;
  bid = (bid & 7) * 288 + (bid >> 3);   // XCD swizzle (2304 blocks, 8 XCDs)
  const int wid = threadIdx.x >> 6;
  const int lane = threadIdx.x & 63;
  const int col = lane & 15, g = lane >> 4;
  const int bh = bid / 72;
  const int rr0 = bid % 72;
  const int qtl = wid >> 1;          // q-tile within block
  const int half = wid & 1;          // key half
  const int b = bh >> 3, h = bh & 7;
  const int s0 = (rr0 * 2 + qtl) * 16;
  const __bf16* Qb = Q + (size_t)bh * S_ * HD_;
  const __bf16* Kb = Kd + (size_t)bh * S_ * HD_;
  const __bf16* Vb = Vt + (size_t)bh * HD_ * S_;

  const b16x8 qf = *(const b16x8*)(Qb + (s0 + col) * HD_ + g * 8);
  // permuted key->row mapping so exp'd score regs match the PV A-fragment layout
  const int kA = ((col >> 2) * 8) + (col & 3);
  const int kbeg = half * (S_ / 2);

  b16x8 onesf;
#pragma unroll
  for (int j = 0; j < 8; ++j) onesf[j] = (__bf16)1.0f;

  f32x4 acc0 = {}, acc1 = {}, accl = {};
  const f32x4 zero = {};

  const __bf16* kptr = Kb + (size_t)(kbeg + kA) * HD_ + g * 8;   // += 32*HD per iter
  const __bf16* vptr = Vb + (size_t)col * S_ + kbeg + g * 8;     // += 32 per iter

  b16x8 ka = *(const b16x8*)(kptr);
  b16x8 kb = *(const b16x8*)(kptr + 4 * HD_);
  b16x8 v0 = *(const b16x8*)(vptr);
  b16x8 v1 = *(const b16x8*)(vptr + 16 * S_);

  for (int it = 0; it < S_ / 2 / 32; ++it) {
    // prefetch next tile (last iter reads in-bounds scratch, never used)
    kptr += 32 * HD_; vptr += 32;
    b16x8 ka_n = *(const b16x8*)(kptr);
    b16x8 kb_n = *(const b16x8*)(kptr + 4 * HD_);
    b16x8 v0_n = *(const b16x8*)(vptr);
    b16x8 v1_n = *(const b16x8*)(vptr + 16 * S_);

    f32x4 sA = mfma_bf16(ka, qf, zero);  // sA[r] = score[key][q=col]
    f32x4 sB = mfma_bf16(kb, qf, zero);
    f32x4 pA, pB;
#pragma unroll
    for (int j = 0; j < 4; ++j) {
      pA[j] = __builtin_amdgcn_exp2f(sA[j]);
      pB[j] = __builtin_amdgcn_exp2f(sB[j]);
    }
    b16x8 pf;
#pragma unroll
    for (int j = 0; j < 4; ++j) { pf[j] = (__bf16)pA[j]; pf[4 + j] = (__bf16)pB[j]; }
    acc0 = mfma_bf16(pf, v0, acc0);     // attended[q][d=col]
    acc1 = mfma_bf16(pf, v1, acc1);     // attended[q][d=16+col]
    accl = mfma_bf16(pf, onesf, accl);  // lsum[q] (replicated over cols)

    ka = ka_n; kb = kb_n; v0 = v0_n; v1 = v1_n;
  }

  // merge the two key-halves via LDS (max-free softmax: partials just add)
  if (half == 1) {
    float* base = mrg[qtl];
    *(f32x4*)(base + col * 16 + g * 4) = acc0;          // [d=col][q=g*4..+3]
    *(f32x4*)(base + (col + 16) * 16 + g * 4) = acc1;   // [d=col+16][q]
    if (col == 0) *(f32x4*)(base + 512 + g * 4) = accl; // lsum[q]
  }
  __syncthreads();
  if (half == 0) {
    const float* base = mrg[qtl];
    f32x4 o0 = *(const f32x4*)(base + col * 16 + g * 4);
    f32x4 o1 = *(const f32x4*)(base + (col + 16) * 16 + g * 4);
    f32x4 ol = *(const f32x4*)(base + 512 + g * 4);
#pragma unroll
    for (int j = 0; j < 4; ++j) {
      const int q = g * 4 + j;
      const float inv = 1.f / (accl[j] + ol[j]);
      const size_t obase = ((size_t)b * S_ + s0 + q) * C_ + h * HD_;
      att[obase + col] = (__bf16)((acc0[j] + o0[j]) * inv);
      att[obase + 16 + col] = (__bf16)((acc1[j] + o1[j]) * inv);
    }
  }
}

// ---------------- K3: output projection + residual -> y (f32, [b][s][c]) ----------------
__global__ __launch_bounds__(256) void k_oproj(
    const __bf16* __restrict__ att, const __bf16* __restrict__ Wob,
    const float* __restrict__ bo, const float* __restrict__ x, float* __restrict__ y) {
  const int wid = threadIdx.x >> 6;
  const int lane = threadIdx.x & 63;
  const int col = lane & 15, g = lane >> 4;
  int r = blockIdx.x;                        // 1152 = 4 * 144 * 2
  const int b = r / 288; r %= 288;
  const int s0 = (r >> 1) * 16;
  const int i0 = (r & 1) * 128 + wid * 32;
  f32x4 acc[2] = {};
  const __bf16* arow = att + ((size_t)b * S_ + s0 + col) * C_ + g * 8;
  const __bf16* wrow = Wob + (size_t)(i0 + col) * C_ + g * 8;
#pragma unroll 2
  for (int kk = 0; kk < 8; ++kk) {
    b16x8 bfr = *(const b16x8*)(arow + kk * 32);
#pragma unroll
    for (int j = 0; j < 2; ++j) {
      b16x8 af = *(const b16x8*)(wrow + (size_t)j * 16 * C_ + kk * 32);
      acc[j] = mfma_bf16(af, bfr, acc[j]);
    }
  }
#pragma unroll
  for (int j = 0; j < 2; ++j) {
#pragma unroll
    for (int rr = 0; rr < 4; ++rr) {
      const int i = i0 + j * 16 + g * 4 + rr;
      const float val = acc[j][rr] + bo[i] + x[((size_t)b * C_ + i) * S_ + s0 + col];
      y[((size_t)b * S_ + s0 + col) * C_ + i] = val;
    }
  }
}

// ---------------- K4: LayerNorm over C + transpose to (B,C,S) ----------------
__global__ __launch_bounds__(256) void k_lnorm(
    const float* __restrict__ y, const float* __restrict__ lnw,
    const float* __restrict__ lnb, float* __restrict__ out) {
  __shared__ float ly[32 * 257];
  __shared__ float lmu[32], lrs[32];
  const int b = blockIdx.x / 72;
  const int s0 = (blockIdx.x % 72) * 32;
  const int tid = threadIdx.x;
  const float* ysrc = y + ((size_t)b * S_ + s0) * C_;
  for (int e = tid; e < 32 * C_; e += 256) {
    const int t = e >> 8, c = e & 255;
    ly[t * 257 + c] = ysrc[e];
  }
  __syncthreads();
  {
    const int t = tid >> 3;
    const int j0 = (tid & 7) * 32;
    float s = 0.f, s2 = 0.f;
#pragma unroll
    for (int j = 0; j < 32; ++j) { const float v = ly[t * 257 + j0 + j]; s += v; s2 += v * v; }
    s += __shfl_xor(s, 1); s2 += __shfl_xor(s2, 1);
    s += __shfl_xor(s, 2); s2 += __shfl_xor(s2, 2);
    s += __shfl_xor(s, 4); s2 += __shfl_xor(s2, 4);
    if ((tid & 7) == 0) {
      const float mu = s * (1.f / 256.f);
      const float var = s2 * (1.f / 256.f) - mu * mu;
      lmu[t] = mu;
      lrs[t] = rsqrtf(var + 1e-5f);
    }
  }
  __syncthreads();
  float* od = out + (size_t)b * C_ * S_ + s0;
  for (int e = tid; e < 32 * C_; e += 256) {
    const int c = e >> 5, t = e & 31;
    const float v = (ly[t * 257 + c] - lmu[t]) * lrs[t] * lnw[c] + lnb[c];
    od[(size_t)c * S_ + t] = v;
  }
}

extern "C" void kernel_launch(void* const* d_in, const int* in_sizes, int n_in,
                              void* d_out, int out_size, void* d_ws, size_t ws_size,
                              hipStream_t stream) {
  const float* x   = (const float*)d_in[0];
  const float* ctx = (const float*)d_in[1];
  const float* Wq  = (const float*)d_in[2];
  const float* bq  = (const float*)d_in[3];
  const float* Wk  = (const float*)d_in[4];
  const float* bk  = (const float*)d_in[5];
  const float* Wv  = (const float*)d_in[6];
  const float* bv  = (const float*)d_in[7];
  const float* Wo  = (const float*)d_in[8];
  const float* bo  = (const float*)d_in[9];
  const float* lnw = (const float*)d_in[10];
  const float* lnb = (const float*)d_in[11];
  float* out = (float*)d_out;

  char* ws = (char*)d_ws;
  __bf16* xT  = (__bf16*)(ws);               // 4,718,592 B (dead after k_qkv)
  __bf16* cT  = (__bf16*)(ws + 4718592);     // 4,718,592 B (dead after k_qkv)
  __bf16* Wb  = (__bf16*)(ws + 9437184);     //   393,216 B
  __bf16* Wob = (__bf16*)(ws + 9830400);     //   131,072 B
  __bf16* Q   = (__bf16*)(ws + 9961472);     // 4,718,592 B
  __bf16* Kd  = (__bf16*)(ws + 14680064);    // 4,718,592 B
  __bf16* Vt  = (__bf16*)(ws + 19398656);    // 4,718,592 B
  __bf16* att = (__bf16*)(ws + 24117248);    // 4,718,592 B
  float*  y   = (float*)(ws);                // 9,437,184 B — reuses dead xT+cT

  k_cvt  <<<4864, 256, 0, stream>>>(x, ctx, Wq, Wk, Wv, Wo, xT, cT, Wb, Wob);
  k_qkv  <<<1728, 256, 0, stream>>>(xT, cT, Wb, bq, bk, bv, Q, Kd, Vt);
  k_attn <<<2304, 256, 0, stream>>>(Q, Kd, Vt, att);
  k_oproj<<<1152, 256, 0, stream>>>(att, Wob, bo, x, y);
  k_lnorm<<< 288, 256, 0, stream>>>(y, lnw, lnb, out);
}

// Round 4
// 214.956 us; speedup vs baseline: 1.4957x; 1.3369x over previous
//
#include <hip/hip_runtime.h>

#define B_ 4
#define C_ 256
#define S_ 2304
#define NH_ 8
#define HD_ 32
// (1/sqrt(32)) * log2(e) folded into Q so softmax is exp2
#define QS_L2E (0.17677669529663687f * 1.4426950408889634f)

typedef __attribute__((ext_vector_type(8))) __bf16 b16x8;
typedef __attribute__((ext_vector_type(4))) __bf16 b16x4;
typedef __attribute__((ext_vector_type(4))) float f32x4;

static __device__ __forceinline__ f32x4 mfma_bf16(b16x8 a, b16x8 b, f32x4 c) {
  return __builtin_amdgcn_mfma_f32_16x16x32_bf16(a, b, c, 0, 0, 0);
}

// ---------------- K0: convert/transpose x,ctx -> bf16 [b][s][c]; W -> bf16 ----------------
__global__ __launch_bounds__(256) void k_cvt(
    const float* __restrict__ x, const float* __restrict__ ctx,
    const float* __restrict__ Wq, const float* __restrict__ Wk,
    const float* __restrict__ Wv, const float* __restrict__ Wo,
    __bf16* __restrict__ xT, __bf16* __restrict__ cT,
    __bf16* __restrict__ Wb, __bf16* __restrict__ Wob) {
  const int bid = blockIdx.x, t = threadIdx.x;
  if (bid < 4608) {
    __shared__ float tile[32][33];
    const int s = bid / 2304;
    int r = bid % 2304;
    const int b = r / 576; r %= 576;
    const int ct = r / 72, st = r % 72;
    const float* src = (s == 0 ? x : ctx) + ((size_t)b * C_ + ct * 32) * S_ + st * 32;
    const int tr = t >> 3, tc = (t & 7) * 4;
    f32x4 v = *(const f32x4*)(src + (size_t)tr * S_ + tc);
    tile[tr][tc] = v[0]; tile[tr][tc + 1] = v[1];
    tile[tr][tc + 2] = v[2]; tile[tr][tc + 3] = v[3];
    __syncthreads();
    __bf16* dst = (s == 0 ? xT : cT) + ((size_t)b * S_ + st * 32 + tr) * C_ + ct * 32 + tc;
    b16x4 o;
#pragma unroll
    for (int j = 0; j < 4; ++j) o[j] = (__bf16)tile[tc + j][tr];
    *(b16x4*)dst = o;
  } else {
    const int wi = bid - 4608;              // 0..255
    const int m = wi >> 6, chunk = wi & 63;
    const float* Wsrc = m == 0 ? Wq : (m == 1 ? Wk : (m == 2 ? Wv : Wo));
    __bf16* Wdst = (m < 3) ? (Wb + m * 65536) : Wob;
    const int e0 = chunk * 1024 + t * 4;
    f32x4 v = *(const f32x4*)(Wsrc + e0);
    b16x4 o;
#pragma unroll
    for (int j = 0; j < 4; ++j) o[j] = (__bf16)v[j];
    *(b16x4*)(Wdst + e0) = o;
  }
}

// ---------------- K1: QKV projections (bf16 in, bf16 out) ----------------
__global__ __launch_bounds__(256) void k_qkv(
    const __bf16* __restrict__ xT, const __bf16* __restrict__ cT,
    const __bf16* __restrict__ Wb,
    const float* __restrict__ bq, const float* __restrict__ bk, const float* __restrict__ bv,
    __bf16* __restrict__ Q, __bf16* __restrict__ Kd, __bf16* __restrict__ Vt) {
  const int iblk = threadIdx.x >> 6;
  const int lane = threadIdx.x & 63;
  const int col = lane & 15, g = lane >> 4;
  int r = blockIdx.x;                        // 1728 = 3 * 4 * 144
  const int p = r / 576; r %= 576;
  const int b = r / 144;
  const int s0 = (r % 144) * 16;
  const __bf16* src = (p == 0 ? xT : cT) + (size_t)b * S_ * C_;
  const __bf16* W = Wb + p * 65536;
  const float* bias = p == 0 ? bq : (p == 1 ? bk : bv);
  const int i0 = iblk * 64;

  f32x4 acc[4] = {};
  const __bf16* brow = src + (size_t)(s0 + col) * C_ + g * 8;
  const __bf16* arow = W + (size_t)(i0 + col) * C_ + g * 8;
#pragma unroll 2
  for (int kk = 0; kk < 8; ++kk) {
    b16x8 bf = *(const b16x8*)(brow + kk * 32);
#pragma unroll
    for (int j = 0; j < 4; ++j) {
      b16x8 af = *(const b16x8*)(arow + (size_t)j * 16 * C_ + kk * 32);
      acc[j] = mfma_bf16(af, bf, acc[j]);
    }
  }
#pragma unroll
  for (int j = 0; j < 4; ++j) {
#pragma unroll
    for (int rr = 0; rr < 4; ++rr) {
      const int i = i0 + j * 16 + g * 4 + rr;
      float val = acc[j][rr] + bias[i];
      const int h = i >> 5, d = i & 31;
      const size_t bh = (size_t)b * NH_ + h;
      if (p == 0)      Q[(bh * S_ + s0 + col) * HD_ + d] = (__bf16)(val * QS_L2E);
      else if (p == 1) Kd[(bh * S_ + s0 + col) * HD_ + d] = (__bf16)val;
      else             Vt[(bh * HD_ + d) * S_ + s0 + col] = (__bf16)val;  // V transposed [d][s]
    }
  }
}

// ---------------- K2: flash attention, 32q/wave, split-K x3, pinned prefetch ----------------
// block = 3 waves (192 thr), each wave: 32 queries x 768 keys. Max-free softmax -> partials add.
__global__ __launch_bounds__(192) void k_attn(
    const __bf16* __restrict__ Q, const __bf16* __restrict__ Kd,
    const __bf16* __restrict__ Vt, __bf16* __restrict__ att) {
  __shared__ float mrg[2][2][528];  // [src wave-1][qt]: acc [d=32][q=16] + lsum[16]
  int bid = blockIdx.x;
  bid = (bid & 7) * 288 + (bid >> 3);   // XCD swizzle (2304 blocks, 8 XCDs, bijective)
  const int wid = threadIdx.x >> 6;     // key third 0..2
  const int lane = threadIdx.x & 63;
  const int col = lane & 15, g = lane >> 4;
  const int bh = bid / 72;
  const int s0 = (bid % 72) * 32;
  const int b = bh >> 3, h = bh & 7;
  const __bf16* Qb = Q + (size_t)bh * S_ * HD_;
  const __bf16* Kb = Kd + (size_t)bh * S_ * HD_;
  const __bf16* Vb = Vt + (size_t)bh * HD_ * S_;

  const b16x8 qf0 = *(const b16x8*)(Qb + (s0 + col) * HD_ + g * 8);
  const b16x8 qf1 = *(const b16x8*)(Qb + (s0 + 16 + col) * HD_ + g * 8);
  // permuted key->row mapping so exp'd score regs match the PV A-fragment layout
  const int kA = ((col >> 2) * 8) + (col & 3);
  const int kbeg = wid * (S_ / 3);

  b16x8 onesf;
#pragma unroll
  for (int j = 0; j < 8; ++j) onesf[j] = (__bf16)1.0f;

  f32x4 a00 = {}, a01 = {}, al0 = {}, a10 = {}, a11 = {}, al1 = {};
  const f32x4 zero = {};

  const __bf16* kptr = Kb + (size_t)(kbeg + kA) * HD_ + g * 8;   // += 32*HD per iter
  const __bf16* vptr = Vb + (size_t)col * S_ + kbeg + g * 8;     // += 32 per iter

  b16x8 ka = *(const b16x8*)(kptr);
  b16x8 kb = *(const b16x8*)(kptr + 4 * HD_);
  b16x8 v0 = *(const b16x8*)(vptr);
  b16x8 v1 = *(const b16x8*)(vptr + 16 * S_);

  for (int it = 0; it < S_ / 3 / 32; ++it) {
    // ---- prefetch next tile (pinned: sched_barrier keeps these issued early) ----
    kptr += 32 * HD_; vptr += 32;
    b16x8 ka_n = *(const b16x8*)(kptr);
    b16x8 kb_n = *(const b16x8*)(kptr + 4 * HD_);
    b16x8 v0_n = *(const b16x8*)(vptr);
    b16x8 v1_n = *(const b16x8*)(vptr + 16 * S_);
    __builtin_amdgcn_sched_barrier(0);

    f32x4 sA0 = mfma_bf16(ka, qf0, zero);  // score[key][q=col], q-tile 0
    f32x4 sB0 = mfma_bf16(kb, qf0, zero);
    f32x4 sA1 = mfma_bf16(ka, qf1, zero);  // q-tile 1
    f32x4 sB1 = mfma_bf16(kb, qf1, zero);
    b16x8 pf0, pf1;
#pragma unroll
    for (int j = 0; j < 4; ++j) {
      pf0[j]     = (__bf16)__builtin_amdgcn_exp2f(sA0[j]);
      pf0[4 + j] = (__bf16)__builtin_amdgcn_exp2f(sB0[j]);
      pf1[j]     = (__bf16)__builtin_amdgcn_exp2f(sA1[j]);
      pf1[4 + j] = (__bf16)__builtin_amdgcn_exp2f(sB1[j]);
    }
    a00 = mfma_bf16(pf0, v0, a00);     // attended[q][d=col]
    a01 = mfma_bf16(pf0, v1, a01);     // attended[q][d=16+col]
    al0 = mfma_bf16(pf0, onesf, al0);  // lsum[q] (replicated over cols)
    a10 = mfma_bf16(pf1, v0, a10);
    a11 = mfma_bf16(pf1, v1, a11);
    al1 = mfma_bf16(pf1, onesf, al1);

    ka = ka_n; kb = kb_n; v0 = v0_n; v1 = v1_n;
  }

  // merge the three key-thirds via LDS (max-free softmax: partials just add)
  if (wid > 0) {
    float* m0 = mrg[wid - 1][0];
    *(f32x4*)(m0 + col * 16 + g * 4) = a00;
    *(f32x4*)(m0 + (col + 16) * 16 + g * 4) = a01;
    if (col == 0) *(f32x4*)(m0 + 512 + g * 4) = al0;
    float* m1 = mrg[wid - 1][1];
    *(f32x4*)(m1 + col * 16 + g * 4) = a10;
    *(f32x4*)(m1 + (col + 16) * 16 + g * 4) = a11;
    if (col == 0) *(f32x4*)(m1 + 512 + g * 4) = al1;
  }
  __syncthreads();
  if (wid == 0) {
#pragma unroll
    for (int qt = 0; qt < 2; ++qt) {
      const float* p0 = mrg[0][qt];
      const float* p1 = mrg[1][qt];
      f32x4 x0 = qt ? a10 : a00, x1 = qt ? a11 : a01, xl = qt ? al1 : al0;
      f32x4 o0a = *(const f32x4*)(p0 + col * 16 + g * 4);
      f32x4 o1a = *(const f32x4*)(p0 + (col + 16) * 16 + g * 4);
      f32x4 ola = *(const f32x4*)(p0 + 512 + g * 4);
      f32x4 o0b = *(const f32x4*)(p1 + col * 16 + g * 4);
      f32x4 o1b = *(const f32x4*)(p1 + (col + 16) * 16 + g * 4);
      f32x4 olb = *(const f32x4*)(p1 + 512 + g * 4);
#pragma unroll
      for (int j = 0; j < 4; ++j) {
        const int q = g * 4 + j;
        const float inv = 1.f / (xl[j] + ola[j] + olb[j]);
        const size_t obase = ((size_t)b * S_ + s0 + qt * 16 + q) * C_ + h * HD_;
        att[obase + col] = (__bf16)((x0[j] + o0a[j] + o0b[j]) * inv);
        att[obase + 16 + col] = (__bf16)((x1[j] + o1a[j] + o1b[j]) * inv);
      }
    }
  }
}

// ---------------- K3: output projection + residual + LayerNorm + transposed store ----------------
// block = 4 waves = all 256 output channels for 16 tokens.
__global__ __launch_bounds__(256) void k_oln(
    const __bf16* __restrict__ att, const __bf16* __restrict__ Wob,
    const float* __restrict__ bo, const float* __restrict__ x,
    const float* __restrict__ lnw, const float* __restrict__ lnb,
    float* __restrict__ out) {
  __shared__ float part[4][2][16];
  __shared__ float lw[256], lb[256];
  const int wid = threadIdx.x >> 6;
  const int lane = threadIdx.x & 63;
  const int col = lane & 15, g = lane >> 4;
  int r = blockIdx.x;                        // 576 = 4 * 144
  const int b = r / 144;
  const int s0 = (r % 144) * 16;
  const int i0 = wid * 64;
  lw[threadIdx.x] = lnw[threadIdx.x];
  lb[threadIdx.x] = lnb[threadIdx.x];

  f32x4 acc[4] = {};
  const __bf16* arow = att + ((size_t)b * S_ + s0 + col) * C_ + g * 8;
  const __bf16* wrow = Wob + (size_t)(i0 + col) * C_ + g * 8;
#pragma unroll 2
  for (int kk = 0; kk < 8; ++kk) {
    b16x8 bfr = *(const b16x8*)(arow + kk * 32);
#pragma unroll
    for (int j = 0; j < 4; ++j) {
      b16x8 af = *(const b16x8*)(wrow + (size_t)j * 16 * C_ + kk * 32);
      acc[j] = mfma_bf16(af, bfr, acc[j]);
    }
  }
  // bias + residual; accumulate LN partials
  float s = 0.f, s2 = 0.f;
#pragma unroll
  for (int j = 0; j < 4; ++j) {
#pragma unroll
    for (int rr = 0; rr < 4; ++rr) {
      const int i = i0 + j * 16 + g * 4 + rr;
      float v = acc[j][rr] + bo[i] + x[((size_t)b * C_ + i) * S_ + s0 + col];
      acc[j][rr] = v;
      s += v; s2 += v * v;
    }
  }
  s += __shfl_xor(s, 16); s2 += __shfl_xor(s2, 16);
  s += __shfl_xor(s, 32); s2 += __shfl_xor(s2, 32);
  if (g == 0) { part[wid][0][col] = s; part[wid][1][col] = s2; }
  __syncthreads();
  float st = part[0][0][col] + part[1][0][col] + part[2][0][col] + part[3][0][col];
  float st2 = part[0][1][col] + part[1][1][col] + part[2][1][col] + part[3][1][col];
  const float mu = st * (1.f / 256.f);
  const float rs = rsqrtf(st2 * (1.f / 256.f) - mu * mu + 1e-5f);
#pragma unroll
  for (int j = 0; j < 4; ++j) {
#pragma unroll
    for (int rr = 0; rr < 4; ++rr) {
      const int i = i0 + j * 16 + g * 4 + rr;
      out[((size_t)b * C_ + i) * S_ + s0 + col] = (acc[j][rr] - mu) * rs * lw[i] + lb[i];
    }
  }
}

extern "C" void kernel_launch(void* const* d_in, const int* in_sizes, int n_in,
                              void* d_out, int out_size, void* d_ws, size_t ws_size,
                              hipStream_t stream) {
  const float* x   = (const float*)d_in[0];
  const float* ctx = (const float*)d_in[1];
  const float* Wq  = (const float*)d_in[2];
  const float* bq  = (const float*)d_in[3];
  const float* Wk  = (const float*)d_in[4];
  const float* bk  = (const float*)d_in[5];
  const float* Wv  = (const float*)d_in[6];
  const float* bv  = (const float*)d_in[7];
  const float* Wo  = (const float*)d_in[8];
  const float* bo  = (const float*)d_in[9];
  const float* lnw = (const float*)d_in[10];
  const float* lnb = (const float*)d_in[11];
  float* out = (float*)d_out;

  char* ws = (char*)d_ws;
  __bf16* xT  = (__bf16*)(ws);               // 4,718,592 B
  __bf16* cT  = (__bf16*)(ws + 4718592);     // 4,718,592 B
  __bf16* Wb  = (__bf16*)(ws + 9437184);     //   393,216 B
  __bf16* Wob = (__bf16*)(ws + 9830400);     //   131,072 B
  __bf16* Q   = (__bf16*)(ws + 9961472);     // 4,718,592 B
  __bf16* Kd  = (__bf16*)(ws + 14680064);    // 4,718,592 B
  __bf16* Vt  = (__bf16*)(ws + 19398656);    // 4,718,592 B
  __bf16* att = (__bf16*)(ws + 24117248);    // 4,718,592 B

  k_cvt  <<<4864, 256, 0, stream>>>(x, ctx, Wq, Wk, Wv, Wo, xT, cT, Wb, Wob);
  k_qkv  <<<1728, 256, 0, stream>>>(xT, cT, Wb, bq, bk, bv, Q, Kd, Vt);
  k_attn <<<2304, 192, 0, stream>>>(Q, Kd, Vt, att);
  k_oln  <<< 576, 256, 0, stream>>>(att, Wob, bo, x, lnw, lnb, out);
}

// Round 5
// 191.857 us; speedup vs baseline: 1.6757x; 1.1204x over previous
//
#include <hip/hip_runtime.h>

#define B_ 4
#define C_ 256
#define S_ 2304
#define NH_ 8
#define HD_ 32
// (1/sqrt(32)) * log2(e) folded into Q so softmax is exp2
#define QS_L2E (0.17677669529663687f * 1.4426950408889634f)

typedef __attribute__((ext_vector_type(8))) __bf16 b16x8;
typedef __attribute__((ext_vector_type(4))) __bf16 b16x4;
typedef __attribute__((ext_vector_type(4))) float f32x4;

static __device__ __forceinline__ f32x4 mfma_bf16(b16x8 a, b16x8 b, f32x4 c) {
  return __builtin_amdgcn_mfma_f32_16x16x32_bf16(a, b, c, 0, 0, 0);
}

// ---------------- K0: convert/transpose x,ctx -> bf16 [b][s][c]; W -> bf16 ----------------
// grid-stride x4: 1216 blocks
__global__ __launch_bounds__(256) void k_cvt(
    const float* __restrict__ x, const float* __restrict__ ctx,
    const float* __restrict__ Wq, const float* __restrict__ Wk,
    const float* __restrict__ Wv, const float* __restrict__ Wo,
    __bf16* __restrict__ xT, __bf16* __restrict__ cT,
    __bf16* __restrict__ Wb, __bf16* __restrict__ Wob) {
  const int bid = blockIdx.x, t = threadIdx.x;
  if (bid < 1152) {
    __shared__ float tile[32][33];
    const int tr = t >> 3, tc = (t & 7) * 4;
#pragma unroll
    for (int i = 0; i < 4; ++i) {
      const int tid4 = bid * 4 + i;
      const int s = tid4 / 2304;
      int r = tid4 % 2304;
      const int b = r / 576; r %= 576;
      const int ct = r / 72, st = r % 72;
      const float* src = (s == 0 ? x : ctx) + ((size_t)b * C_ + ct * 32) * S_ + st * 32;
      if (i) __syncthreads();
      f32x4 v = *(const f32x4*)(src + (size_t)tr * S_ + tc);
      tile[tr][tc] = v[0]; tile[tr][tc + 1] = v[1];
      tile[tr][tc + 2] = v[2]; tile[tr][tc + 3] = v[3];
      __syncthreads();
      __bf16* dst = (s == 0 ? xT : cT) + ((size_t)b * S_ + st * 32 + tr) * C_ + ct * 32 + tc;
      b16x4 o;
#pragma unroll
      for (int j = 0; j < 4; ++j) o[j] = (__bf16)tile[tc + j][tr];
      *(b16x4*)dst = o;
    }
  } else {
    const int bid2 = bid - 1152;            // 0..63
#pragma unroll
    for (int i = 0; i < 4; ++i) {
      const int wi = bid2 * 4 + i;          // 0..255
      const int m = wi >> 6, chunk = wi & 63;
      const float* Wsrc = m == 0 ? Wq : (m == 1 ? Wk : (m == 2 ? Wv : Wo));
      __bf16* Wdst = (m < 3) ? (Wb + m * 65536) : Wob;
      const int e0 = chunk * 1024 + t * 4;
      f32x4 v = *(const f32x4*)(Wsrc + e0);
      b16x4 o;
#pragma unroll
      for (int j = 0; j < 4; ++j) o[j] = (__bf16)v[j];
      *(b16x4*)(Wdst + e0) = o;
    }
  }
}

// ---------------- K1: QKV projections, 32 tokens/wave, pinned prefetch ----------------
__global__ __launch_bounds__(256) void k_qkv(
    const __bf16* __restrict__ xT, const __bf16* __restrict__ cT,
    const __bf16* __restrict__ Wb,
    const float* __restrict__ bq, const float* __restrict__ bk, const float* __restrict__ bv,
    __bf16* __restrict__ Q, __bf16* __restrict__ Kd, __bf16* __restrict__ Vt) {
  const int iblk = threadIdx.x >> 6;
  const int lane = threadIdx.x & 63;
  const int col = lane & 15, g = lane >> 4;
  int r = blockIdx.x;                        // 864 = 3 * 4 * 72
  const int p = r / 288; r %= 288;
  const int b = r / 72;
  const int s0 = (r % 72) * 32;
  const __bf16* src = (p == 0 ? xT : cT) + (size_t)b * S_ * C_;
  const __bf16* W = Wb + p * 65536;
  const float* bias = p == 0 ? bq : (p == 1 ? bk : bv);
  const int i0 = iblk * 64;

  f32x4 acc[2][4] = {};
  const __bf16* brow0 = src + (size_t)(s0 + col) * C_ + g * 8;
  const __bf16* brow1 = brow0 + 16 * C_;
  const __bf16* arow = W + (size_t)(i0 + col) * C_ + g * 8;

  b16x8 bf0 = *(const b16x8*)(brow0);
  b16x8 bf1 = *(const b16x8*)(brow1);
  b16x8 af0 = *(const b16x8*)(arow);
  b16x8 af1 = *(const b16x8*)(arow + (size_t)16 * C_);
  b16x8 af2 = *(const b16x8*)(arow + (size_t)32 * C_);
  b16x8 af3 = *(const b16x8*)(arow + (size_t)48 * C_);

  for (int kk = 0; kk < 8; ++kk) {
    const int nk = (kk + 1) * 32;
    b16x8 nbf0 = *(const b16x8*)(brow0 + nk);
    b16x8 nbf1 = *(const b16x8*)(brow1 + nk);
    b16x8 naf0 = *(const b16x8*)(arow + nk);
    b16x8 naf1 = *(const b16x8*)(arow + (size_t)16 * C_ + nk);
    b16x8 naf2 = *(const b16x8*)(arow + (size_t)32 * C_ + nk);
    b16x8 naf3 = *(const b16x8*)(arow + (size_t)48 * C_ + nk);
    __builtin_amdgcn_sched_barrier(0);
    acc[0][0] = mfma_bf16(af0, bf0, acc[0][0]);
    acc[0][1] = mfma_bf16(af1, bf0, acc[0][1]);
    acc[0][2] = mfma_bf16(af2, bf0, acc[0][2]);
    acc[0][3] = mfma_bf16(af3, bf0, acc[0][3]);
    acc[1][0] = mfma_bf16(af0, bf1, acc[1][0]);
    acc[1][1] = mfma_bf16(af1, bf1, acc[1][1]);
    acc[1][2] = mfma_bf16(af2, bf1, acc[1][2]);
    acc[1][3] = mfma_bf16(af3, bf1, acc[1][3]);
    bf0 = nbf0; bf1 = nbf1; af0 = naf0; af1 = naf1; af2 = naf2; af3 = naf3;
  }
#pragma unroll
  for (int tf = 0; tf < 2; ++tf) {
#pragma unroll
    for (int j = 0; j < 4; ++j) {
#pragma unroll
      for (int rr = 0; rr < 4; ++rr) {
        const int i = i0 + j * 16 + g * 4 + rr;
        float val = acc[tf][j][rr] + bias[i];
        const int h = i >> 5, d = i & 31;
        const size_t bh = (size_t)b * NH_ + h;
        const int tok = s0 + tf * 16 + col;
        if (p == 0)      Q[(bh * S_ + tok) * HD_ + d] = (__bf16)(val * QS_L2E);
        else if (p == 1) Kd[(bh * S_ + tok) * HD_ + d] = (__bf16)val;
        else             Vt[(bh * HD_ + d) * S_ + tok] = (__bf16)val;  // V transposed [d][s]
      }
    }
  }
}

// ---------------- K2: flash attention, 64q/wave, split-K x3, pinned prefetch ----------------
__global__ __launch_bounds__(192) void k_attn(
    const __bf16* __restrict__ Q, const __bf16* __restrict__ Kd,
    const __bf16* __restrict__ Vt, __bf16* __restrict__ att) {
  __shared__ float mrg[2][4][528];  // [src wave-1][qt]: acc [d=32][q=16] + lsum[16]
  int bid = blockIdx.x;
  bid = (bid & 7) * 144 + (bid >> 3);   // XCD swizzle (1152 blocks, 8 XCDs, bijective)
  const int wid = threadIdx.x >> 6;     // key third 0..2
  const int lane = threadIdx.x & 63;
  const int col = lane & 15, g = lane >> 4;
  const int bh = bid / 36;
  const int s0 = (bid % 36) * 64;
  const int b = bh >> 3, h = bh & 7;
  const __bf16* Qb = Q + (size_t)bh * S_ * HD_;
  const __bf16* Kb = Kd + (size_t)bh * S_ * HD_;
  const __bf16* Vb = Vt + (size_t)bh * HD_ * S_;

  b16x8 qfr[4];
#pragma unroll
  for (int q = 0; q < 4; ++q)
    qfr[q] = *(const b16x8*)(Qb + (size_t)(s0 + q * 16 + col) * HD_ + g * 8);
  // permuted key->row mapping so exp'd score regs match the PV A-fragment layout
  const int kA = ((col >> 2) * 8) + (col & 3);
  const int kbeg = wid * (S_ / 3);

  b16x8 onesf;
#pragma unroll
  for (int j = 0; j < 8; ++j) onesf[j] = (__bf16)1.0f;

  f32x4 acc0[4] = {}, acc1[4] = {}, accl[4] = {};
  const f32x4 zero = {};

  const __bf16* kptr = Kb + (size_t)(kbeg + kA) * HD_ + g * 8;   // += 32*HD per iter
  const __bf16* vptr = Vb + (size_t)col * S_ + kbeg + g * 8;     // += 32 per iter

  b16x8 ka = *(const b16x8*)(kptr);
  b16x8 kb = *(const b16x8*)(kptr + 4 * HD_);
  b16x8 v0 = *(const b16x8*)(vptr);
  b16x8 v1 = *(const b16x8*)(vptr + 16 * S_);

  for (int it = 0; it < S_ / 3 / 32; ++it) {
    // ---- prefetch next tile (pinned ahead of compute) ----
    kptr += 32 * HD_; vptr += 32;
    b16x8 ka_n = *(const b16x8*)(kptr);
    b16x8 kb_n = *(const b16x8*)(kptr + 4 * HD_);
    b16x8 v0_n = *(const b16x8*)(vptr);
    b16x8 v1_n = *(const b16x8*)(vptr + 16 * S_);
    __builtin_amdgcn_sched_barrier(0);

#pragma unroll
    for (int q = 0; q < 4; ++q) {
      f32x4 sA = mfma_bf16(ka, qfr[q], zero);  // score[key][q=col]
      f32x4 sB = mfma_bf16(kb, qfr[q], zero);
      b16x8 pf;
#pragma unroll
      for (int j = 0; j < 4; ++j) {
        pf[j]     = (__bf16)__builtin_amdgcn_exp2f(sA[j]);
        pf[4 + j] = (__bf16)__builtin_amdgcn_exp2f(sB[j]);
      }
      acc0[q] = mfma_bf16(pf, v0, acc0[q]);     // attended[q][d=col]
      acc1[q] = mfma_bf16(pf, v1, acc1[q]);     // attended[q][d=16+col]
      accl[q] = mfma_bf16(pf, onesf, accl[q]);  // lsum[q] (replicated over cols)
    }
    ka = ka_n; kb = kb_n; v0 = v0_n; v1 = v1_n;
  }

  // merge the three key-thirds via LDS (max-free softmax: partials just add)
  if (wid > 0) {
#pragma unroll
    for (int qt = 0; qt < 4; ++qt) {
      float* m0 = mrg[wid - 1][qt];
      *(f32x4*)(m0 + col * 16 + g * 4) = acc0[qt];
      *(f32x4*)(m0 + (col + 16) * 16 + g * 4) = acc1[qt];
      if (col == 0) *(f32x4*)(m0 + 512 + g * 4) = accl[qt];
    }
  }
  __syncthreads();
  if (wid == 0) {
#pragma unroll
    for (int qt = 0; qt < 4; ++qt) {
      const float* p0 = mrg[0][qt];
      const float* p1 = mrg[1][qt];
      f32x4 o0a = *(const f32x4*)(p0 + col * 16 + g * 4);
      f32x4 o1a = *(const f32x4*)(p0 + (col + 16) * 16 + g * 4);
      f32x4 ola = *(const f32x4*)(p0 + 512 + g * 4);
      f32x4 o0b = *(const f32x4*)(p1 + col * 16 + g * 4);
      f32x4 o1b = *(const f32x4*)(p1 + (col + 16) * 16 + g * 4);
      f32x4 olb = *(const f32x4*)(p1 + 512 + g * 4);
#pragma unroll
      for (int j = 0; j < 4; ++j) {
        const int q = g * 4 + j;
        const float inv = 1.f / (accl[qt][j] + ola[j] + olb[j]);
        const size_t obase = ((size_t)b * S_ + s0 + qt * 16 + q) * C_ + h * HD_;
        att[obase + col] = (__bf16)((acc0[qt][j] + o0a[j] + o0b[j]) * inv);
        att[obase + 16 + col] = (__bf16)((acc1[qt][j] + o1a[j] + o1b[j]) * inv);
      }
    }
  }
}

// ---------------- K3: output projection + residual + LayerNorm + transposed store ----------------
__global__ __launch_bounds__(256) void k_oln(
    const __bf16* __restrict__ att, const __bf16* __restrict__ Wob,
    const float* __restrict__ bo, const float* __restrict__ x,
    const float* __restrict__ lnw, const float* __restrict__ lnb,
    float* __restrict__ out) {
  __shared__ float part[4][2][16];
  __shared__ float lw[256], lb[256];
  const int wid = threadIdx.x >> 6;
  const int lane = threadIdx.x & 63;
  const int col = lane & 15, g = lane >> 4;
  int r = blockIdx.x;                        // 576 = 4 * 144
  const int b = r / 144;
  const int s0 = (r % 144) * 16;
  const int i0 = wid * 64;
  lw[threadIdx.x] = lnw[threadIdx.x];
  lb[threadIdx.x] = lnb[threadIdx.x];

  f32x4 acc[4] = {};
  const __bf16* arow = att + ((size_t)b * S_ + s0 + col) * C_ + g * 8;
  const __bf16* wrow = Wob + (size_t)(i0 + col) * C_ + g * 8;

  b16x8 bfr = *(const b16x8*)(arow);
  b16x8 af0 = *(const b16x8*)(wrow);
  b16x8 af1 = *(const b16x8*)(wrow + (size_t)16 * C_);
  b16x8 af2 = *(const b16x8*)(wrow + (size_t)32 * C_);
  b16x8 af3 = *(const b16x8*)(wrow + (size_t)48 * C_);

  for (int kk = 0; kk < 8; ++kk) {
    const int nk = (kk + 1) * 32;
    b16x8 nbfr = *(const b16x8*)(arow + nk);
    b16x8 naf0 = *(const b16x8*)(wrow + nk);
    b16x8 naf1 = *(const b16x8*)(wrow + (size_t)16 * C_ + nk);
    b16x8 naf2 = *(const b16x8*)(wrow + (size_t)32 * C_ + nk);
    b16x8 naf3 = *(const b16x8*)(wrow + (size_t)48 * C_ + nk);
    __builtin_amdgcn_sched_barrier(0);
    acc[0] = mfma_bf16(af0, bfr, acc[0]);
    acc[1] = mfma_bf16(af1, bfr, acc[1]);
    acc[2] = mfma_bf16(af2, bfr, acc[2]);
    acc[3] = mfma_bf16(af3, bfr, acc[3]);
    bfr = nbfr; af0 = naf0; af1 = naf1; af2 = naf2; af3 = naf3;
  }
  // bias + residual; accumulate LN partials
  float s = 0.f, s2 = 0.f;
#pragma unroll
  for (int j = 0; j < 4; ++j) {
#pragma unroll
    for (int rr = 0; rr < 4; ++rr) {
      const int i = i0 + j * 16 + g * 4 + rr;
      float v = acc[j][rr] + bo[i] + x[((size_t)b * C_ + i) * S_ + s0 + col];
      acc[j][rr] = v;
      s += v; s2 += v * v;
    }
  }
  s += __shfl_xor(s, 16); s2 += __shfl_xor(s2, 16);
  s += __shfl_xor(s, 32); s2 += __shfl_xor(s2, 32);
  if (g == 0) { part[wid][0][col] = s; part[wid][1][col] = s2; }
  __syncthreads();
  float st = part[0][0][col] + part[1][0][col] + part[2][0][col] + part[3][0][col];
  float st2 = part[0][1][col] + part[1][1][col] + part[2][1][col] + part[3][1][col];
  const float mu = st * (1.f / 256.f);
  const float rs = rsqrtf(st2 * (1.f / 256.f) - mu * mu + 1e-5f);
#pragma unroll
  for (int j = 0; j < 4; ++j) {
#pragma unroll
    for (int rr = 0; rr < 4; ++rr) {
      const int i = i0 + j * 16 + g * 4 + rr;
      out[((size_t)b * C_ + i) * S_ + s0 + col] = (acc[j][rr] - mu) * rs * lw[i] + lb[i];
    }
  }
}

extern "C" void kernel_launch(void* const* d_in, const int* in_sizes, int n_in,
                              void* d_out, int out_size, void* d_ws, size_t ws_size,
                              hipStream_t stream) {
  const float* x   = (const float*)d_in[0];
  const float* ctx = (const float*)d_in[1];
  const float* Wq  = (const float*)d_in[2];
  const float* bq  = (const float*)d_in[3];
  const float* Wk  = (const float*)d_in[4];
  const float* bk  = (const float*)d_in[5];
  const float* Wv  = (const float*)d_in[6];
  const float* bv  = (const float*)d_in[7];
  const float* Wo  = (const float*)d_in[8];
  const float* bo  = (const float*)d_in[9];
  const float* lnw = (const float*)d_in[10];
  const float* lnb = (const float*)d_in[11];
  float* out = (float*)d_out;

  // layout ordered so every depth-1 prefetch overrun lands in a following buffer
  // (Q last: it is never prefetch-read)
  char* ws = (char*)d_ws;
  __bf16* xT  = (__bf16*)(ws);               // 4,718,592 B
  __bf16* cT  = (__bf16*)(ws + 4718592);     // 4,718,592 B
  __bf16* Wb  = (__bf16*)(ws + 9437184);     //   393,216 B
  __bf16* Wob = (__bf16*)(ws + 9830400);     //   131,072 B
  __bf16* Kd  = (__bf16*)(ws + 9961472);     // 4,718,592 B
  __bf16* Vt  = (__bf16*)(ws + 14680064);    // 4,718,592 B
  __bf16* att = (__bf16*)(ws + 19398656);    // 4,718,592 B
  __bf16* Q   = (__bf16*)(ws + 24117248);    // 4,718,592 B

  k_cvt  <<<1216, 256, 0, stream>>>(x, ctx, Wq, Wk, Wv, Wo, xT, cT, Wb, Wob);
  k_qkv  <<< 864, 256, 0, stream>>>(xT, cT, Wb, bq, bk, bv, Q, Kd, Vt);
  k_attn <<<1152, 192, 0, stream>>>(Q, Kd, Vt, att);
  k_oln  <<< 576, 256, 0, stream>>>(att, Wob, bo, x, lnw, lnb, out);
}

// Round 6
// 173.856 us; speedup vs baseline: 1.8492x; 1.1035x over previous
//
#include <hip/hip_runtime.h>

#define B_ 4
#define C_ 256
#define S_ 2304
#define NH_ 8
#define HD_ 32
// (1/sqrt(32)) * log2(e) folded into Q so softmax is exp2
#define QS_L2E (0.17677669529663687f * 1.4426950408889634f)

typedef __attribute__((ext_vector_type(8))) __bf16 b16x8;
typedef __attribute__((ext_vector_type(4))) __bf16 b16x4;
typedef __attribute__((ext_vector_type(4))) float f32x4;
typedef __attribute__((ext_vector_type(4))) unsigned u32x4;

static __device__ __forceinline__ f32x4 mfma_bf16(b16x8 a, b16x8 b, f32x4 c) {
  return __builtin_amdgcn_mfma_f32_16x16x32_bf16(a, b, c, 0, 0, 0);
}

// ---------------- K0: W -> bf16 (weights only; x/ctx transpose fused into k_qkv) ----------------
__global__ __launch_bounds__(256) void k_cvtw(
    const float* __restrict__ Wq, const float* __restrict__ Wk,
    const float* __restrict__ Wv, const float* __restrict__ Wo,
    __bf16* __restrict__ Wb, __bf16* __restrict__ Wob) {
  const int e = blockIdx.x * 1024 + threadIdx.x * 4;
  const float* s;
  __bf16* d;
  if (e < 196608) {
    const int m = e >> 16;
    s = (m == 0 ? Wq : (m == 1 ? Wk : Wv)) + (e & 65535);
    d = Wb + e;
  } else {
    s = Wo + (e - 196608);
    d = Wob + (e - 196608);
  }
  f32x4 v = *(const f32x4*)s;
  b16x4 o;
#pragma unroll
  for (int j = 0; j < 4; ++j) o[j] = (__bf16)v[j];
  *(b16x4*)d = o;
}

// ---------------- K1: QKV projections, fused transpose-stage + GEMM ----------------
// block = (p, b, 32 tokens); stages x/ctx [256c][32s] f32 -> LDS [32s][256c] bf16, then 4 waves x 64 ch.
__global__ __launch_bounds__(256) void k_qkv(
    const float* __restrict__ x, const float* __restrict__ ctx,
    const __bf16* __restrict__ Wb,
    const float* __restrict__ bq, const float* __restrict__ bk, const float* __restrict__ bv,
    __bf16* __restrict__ Q, __bf16* __restrict__ Kd, __bf16* __restrict__ Vt) {
  __shared__ __bf16 lx[33][264];  // +1 row / +8 pad: in-bounds for wrap prefetch, bank spread
  const int t = threadIdx.x;
  const int iblk = t >> 6;
  const int lane = t & 63;
  const int col = lane & 15, g = lane >> 4;
  int r = blockIdx.x;                        // 864 = 3 * 4 * 72
  const int p = r / 288; r %= 288;
  const int b = r / 72;
  const int s0 = (r % 72) * 32;
  const float* src = (p == 0 ? x : ctx) + (size_t)b * C_ * S_ + s0;
  const __bf16* W = Wb + p * 65536;
  const float* bias = p == 0 ? bq : (p == 1 ? bk : bv);
  const int i0 = iblk * 64;
  const __bf16* arow = W + (size_t)(i0 + col) * C_ + g * 8;

  // issue first W fragments before staging so their latency overlaps the stage
  b16x8 af0 = *(const b16x8*)(arow);
  b16x8 af1 = *(const b16x8*)(arow + (size_t)16 * C_);
  b16x8 af2 = *(const b16x8*)(arow + (size_t)32 * C_);
  b16x8 af3 = *(const b16x8*)(arow + (size_t)48 * C_);

  // stage: 8 iters, each covers 32 c-rows x 32 s (8 threads x f32x4 per row)
  {
    const int tr = t >> 3, tc = (t & 7) * 4;
#pragma unroll
    for (int j = 0; j < 8; ++j) {
      const int c = j * 32 + tr;
      f32x4 v = *(const f32x4*)(src + (size_t)c * S_ + tc);
#pragma unroll
      for (int jj = 0; jj < 4; ++jj) lx[tc + jj][c] = (__bf16)v[jj];
    }
  }
  __syncthreads();

  f32x4 acc[2][4] = {};
  b16x8 bf0 = *(const b16x8*)(&lx[col][g * 8]);
  b16x8 bf1 = *(const b16x8*)(&lx[16 + col][g * 8]);

  for (int kk = 0; kk < 8; ++kk) {
    const int nk = ((kk + 1) & 7) * 32;    // wrap: last iter re-reads kk=0 (discarded)
    b16x8 nbf0 = *(const b16x8*)(&lx[col][nk + g * 8]);
    b16x8 nbf1 = *(const b16x8*)(&lx[16 + col][nk + g * 8]);
    b16x8 naf0 = *(const b16x8*)(arow + nk);
    b16x8 naf1 = *(const b16x8*)(arow + (size_t)16 * C_ + nk);
    b16x8 naf2 = *(const b16x8*)(arow + (size_t)32 * C_ + nk);
    b16x8 naf3 = *(const b16x8*)(arow + (size_t)48 * C_ + nk);
    __builtin_amdgcn_sched_barrier(0);
    acc[0][0] = mfma_bf16(af0, bf0, acc[0][0]);
    acc[0][1] = mfma_bf16(af1, bf0, acc[0][1]);
    acc[0][2] = mfma_bf16(af2, bf0, acc[0][2]);
    acc[0][3] = mfma_bf16(af3, bf0, acc[0][3]);
    acc[1][0] = mfma_bf16(af0, bf1, acc[1][0]);
    acc[1][1] = mfma_bf16(af1, bf1, acc[1][1]);
    acc[1][2] = mfma_bf16(af2, bf1, acc[1][2]);
    acc[1][3] = mfma_bf16(af3, bf1, acc[1][3]);
    bf0 = nbf0; bf1 = nbf1; af0 = naf0; af1 = naf1; af2 = naf2; af3 = naf3;
  }
#pragma unroll
  for (int tf = 0; tf < 2; ++tf) {
#pragma unroll
    for (int j = 0; j < 4; ++j) {
#pragma unroll
      for (int rr = 0; rr < 4; ++rr) {
        const int i = i0 + j * 16 + g * 4 + rr;
        float val = acc[tf][j][rr] + bias[i];
        const int h = i >> 5, d = i & 31;
        const size_t bh = (size_t)b * NH_ + h;
        const int tok = s0 + tf * 16 + col;
        if (p == 0)      Q[(bh * S_ + tok) * HD_ + d] = (__bf16)(val * QS_L2E);
        else if (p == 1) Kd[(bh * S_ + tok) * HD_ + d] = (__bf16)val;
        else             Vt[(bh * HD_ + d) * S_ + tok] = (__bf16)val;  // V transposed [d][s]
      }
    }
  }
}

// ---------------- K2: flash attention, 64q/wave, split-K x4, cvt_pk softmax ----------------
__global__ __launch_bounds__(256) void k_attn(
    const __bf16* __restrict__ Q, const __bf16* __restrict__ Kd,
    const __bf16* __restrict__ Vt, __bf16* __restrict__ att) {
  __shared__ float mrg[3][4][528];  // [src wave-1][qt]: acc [d=32][q=16] + lsum[16]
  int bid = blockIdx.x;
  bid = (bid & 7) * 144 + (bid >> 3);   // XCD swizzle (1152 blocks, 8 XCDs, bijective)
  const int wid = threadIdx.x >> 6;     // key quarter 0..3
  const int lane = threadIdx.x & 63;
  const int col = lane & 15, g = lane >> 4;
  const int bh = bid / 36;
  const int s0 = (bid % 36) * 64;
  const int b = bh >> 3, h = bh & 7;
  const __bf16* Qb = Q + (size_t)bh * S_ * HD_;
  const __bf16* Kb = Kd + (size_t)bh * S_ * HD_;
  const __bf16* Vb = Vt + (size_t)bh * HD_ * S_;

  b16x8 qfr[4];
#pragma unroll
  for (int q = 0; q < 4; ++q)
    qfr[q] = *(const b16x8*)(Qb + (size_t)(s0 + q * 16 + col) * HD_ + g * 8);
  // permuted key->row mapping so exp'd score regs match the PV A-fragment layout
  const int kA = ((col >> 2) * 8) + (col & 3);
  const int kbeg = wid * (S_ / 4);

  b16x8 onesf;
#pragma unroll
  for (int j = 0; j < 8; ++j) onesf[j] = (__bf16)1.0f;

  f32x4 acc0[4] = {}, acc1[4] = {}, accl[4] = {};
  const f32x4 zero = {};

  const __bf16* kptr = Kb + (size_t)(kbeg + kA) * HD_ + g * 8;   // += 32*HD per iter
  const __bf16* vptr = Vb + (size_t)col * S_ + kbeg + g * 8;     // += 32 per iter

  b16x8 ka = *(const b16x8*)(kptr);
  b16x8 kb = *(const b16x8*)(kptr + 4 * HD_);
  b16x8 v0 = *(const b16x8*)(vptr);
  b16x8 v1 = *(const b16x8*)(vptr + 16 * S_);

  for (int it = 0; it < S_ / 4 / 32; ++it) {
    // ---- prefetch next tile (pinned ahead of compute) ----
    kptr += 32 * HD_; vptr += 32;
    b16x8 ka_n = *(const b16x8*)(kptr);
    b16x8 kb_n = *(const b16x8*)(kptr + 4 * HD_);
    b16x8 v0_n = *(const b16x8*)(vptr);
    b16x8 v1_n = *(const b16x8*)(vptr + 16 * S_);
    __builtin_amdgcn_sched_barrier(0);

#pragma unroll
    for (int q = 0; q < 4; ++q) {
      f32x4 sA = mfma_bf16(ka, qfr[q], zero);  // score[key][q=col]
      f32x4 sB = mfma_bf16(kb, qfr[q], zero);
      float eA0 = __builtin_amdgcn_exp2f(sA[0]);
      float eA1 = __builtin_amdgcn_exp2f(sA[1]);
      float eA2 = __builtin_amdgcn_exp2f(sA[2]);
      float eA3 = __builtin_amdgcn_exp2f(sA[3]);
      float eB0 = __builtin_amdgcn_exp2f(sB[0]);
      float eB1 = __builtin_amdgcn_exp2f(sB[1]);
      float eB2 = __builtin_amdgcn_exp2f(sB[2]);
      float eB3 = __builtin_amdgcn_exp2f(sB[3]);
      unsigned w0, w1, w2, w3;
      asm("v_cvt_pk_bf16_f32 %0, %1, %2" : "=v"(w0) : "v"(eA0), "v"(eA1));
      asm("v_cvt_pk_bf16_f32 %0, %1, %2" : "=v"(w1) : "v"(eA2), "v"(eA3));
      asm("v_cvt_pk_bf16_f32 %0, %1, %2" : "=v"(w2) : "v"(eB0), "v"(eB1));
      asm("v_cvt_pk_bf16_f32 %0, %1, %2" : "=v"(w3) : "v"(eB2), "v"(eB3));
      u32x4 pw = {w0, w1, w2, w3};
      b16x8 pf = __builtin_bit_cast(b16x8, pw);
      acc0[q] = mfma_bf16(pf, v0, acc0[q]);     // attended[q][d=col]
      acc1[q] = mfma_bf16(pf, v1, acc1[q]);     // attended[q][d=16+col]
      accl[q] = mfma_bf16(pf, onesf, accl[q]);  // lsum[q] (replicated over cols)
    }
    ka = ka_n; kb = kb_n; v0 = v0_n; v1 = v1_n;
  }

  // merge the four key-quarters via LDS (max-free softmax: partials just add)
  if (wid > 0) {
#pragma unroll
    for (int qt = 0; qt < 4; ++qt) {
      float* m0 = mrg[wid - 1][qt];
      *(f32x4*)(m0 + col * 16 + g * 4) = acc0[qt];
      *(f32x4*)(m0 + (col + 16) * 16 + g * 4) = acc1[qt];
      if (col == 0) *(f32x4*)(m0 + 512 + g * 4) = accl[qt];
    }
  }
  __syncthreads();
  if (wid == 0) {
#pragma unroll
    for (int qt = 0; qt < 4; ++qt) {
      f32x4 t0 = acc0[qt], t1 = acc1[qt], tl = accl[qt];
#pragma unroll
      for (int m = 0; m < 3; ++m) {
        const float* pm = mrg[m][qt];
        t0 += *(const f32x4*)(pm + col * 16 + g * 4);
        t1 += *(const f32x4*)(pm + (col + 16) * 16 + g * 4);
        tl += *(const f32x4*)(pm + 512 + g * 4);
      }
#pragma unroll
      for (int j = 0; j < 4; ++j) {
        const int q = g * 4 + j;
        const float inv = 1.f / tl[j];
        const size_t obase = ((size_t)b * S_ + s0 + qt * 16 + q) * C_ + h * HD_;
        att[obase + col] = (__bf16)(t0[j] * inv);
        att[obase + 16 + col] = (__bf16)(t1[j] * inv);
      }
    }
  }
}

// ---------------- K3: output projection + residual + LayerNorm + transposed store ----------------
__global__ __launch_bounds__(256) void k_oln(
    const __bf16* __restrict__ att, const __bf16* __restrict__ Wob,
    const float* __restrict__ bo, const float* __restrict__ x,
    const float* __restrict__ lnw, const float* __restrict__ lnb,
    float* __restrict__ out) {
  __shared__ float part[4][2][16];
  __shared__ float lw[256], lb[256];
  const int wid = threadIdx.x >> 6;
  const int lane = threadIdx.x & 63;
  const int col = lane & 15, g = lane >> 4;
  int r = blockIdx.x;                        // 576 = 4 * 144
  const int b = r / 144;
  const int s0 = (r % 144) * 16;
  const int i0 = wid * 64;
  lw[threadIdx.x] = lnw[threadIdx.x];
  lb[threadIdx.x] = lnb[threadIdx.x];

  f32x4 acc[4] = {};
  const __bf16* arow = att + ((size_t)b * S_ + s0 + col) * C_ + g * 8;
  const __bf16* wrow = Wob + (size_t)(i0 + col) * C_ + g * 8;

  b16x8 bfr = *(const b16x8*)(arow);
  b16x8 af0 = *(const b16x8*)(wrow);
  b16x8 af1 = *(const b16x8*)(wrow + (size_t)16 * C_);
  b16x8 af2 = *(const b16x8*)(wrow + (size_t)32 * C_);
  b16x8 af3 = *(const b16x8*)(wrow + (size_t)48 * C_);

  for (int kk = 0; kk < 8; ++kk) {
    const int nk = ((kk + 1) & 7) * 32;
    b16x8 nbfr = *(const b16x8*)(arow + nk);
    b16x8 naf0 = *(const b16x8*)(wrow + nk);
    b16x8 naf1 = *(const b16x8*)(wrow + (size_t)16 * C_ + nk);
    b16x8 naf2 = *(const b16x8*)(wrow + (size_t)32 * C_ + nk);
    b16x8 naf3 = *(const b16x8*)(wrow + (size_t)48 * C_ + nk);
    __builtin_amdgcn_sched_barrier(0);
    acc[0] = mfma_bf16(af0, bfr, acc[0]);
    acc[1] = mfma_bf16(af1, bfr, acc[1]);
    acc[2] = mfma_bf16(af2, bfr, acc[2]);
    acc[3] = mfma_bf16(af3, bfr, acc[3]);
    bfr = nbfr; af0 = naf0; af1 = naf1; af2 = naf2; af3 = naf3;
  }
  // bias + residual; accumulate LN partials
  float s = 0.f, s2 = 0.f;
#pragma unroll
  for (int j = 0; j < 4; ++j) {
#pragma unroll
    for (int rr = 0; rr < 4; ++rr) {
      const int i = i0 + j * 16 + g * 4 + rr;
      float v = acc[j][rr] + bo[i] + x[((size_t)b * C_ + i) * S_ + s0 + col];
      acc[j][rr] = v;
      s += v; s2 += v * v;
    }
  }
  s += __shfl_xor(s, 16); s2 += __shfl_xor(s2, 16);
  s += __shfl_xor(s, 32); s2 += __shfl_xor(s2, 32);
  if (g == 0) { part[wid][0][col] = s; part[wid][1][col] = s2; }
  __syncthreads();
  float st = part[0][0][col] + part[1][0][col] + part[2][0][col] + part[3][0][col];
  float st2 = part[0][1][col] + part[1][1][col] + part[2][1][col] + part[3][1][col];
  const float mu = st * (1.f / 256.f);
  const float rs = rsqrtf(st2 * (1.f / 256.f) - mu * mu + 1e-5f);
#pragma unroll
  for (int j = 0; j < 4; ++j) {
#pragma unroll
    for (int rr = 0; rr < 4; ++rr) {
      const int i = i0 + j * 16 + g * 4 + rr;
      out[((size_t)b * C_ + i) * S_ + s0 + col] = (acc[j][rr] - mu) * rs * lw[i] + lb[i];
    }
  }
}

extern "C" void kernel_launch(void* const* d_in, const int* in_sizes, int n_in,
                              void* d_out, int out_size, void* d_ws, size_t ws_size,
                              hipStream_t stream) {
  const float* x   = (const float*)d_in[0];
  const float* ctx = (const float*)d_in[1];
  const float* Wq  = (const float*)d_in[2];
  const float* bq  = (const float*)d_in[3];
  const float* Wk  = (const float*)d_in[4];
  const float* bk  = (const float*)d_in[5];
  const float* Wv  = (const float*)d_in[6];
  const float* bv  = (const float*)d_in[7];
  const float* Wo  = (const float*)d_in[8];
  const float* bo  = (const float*)d_in[9];
  const float* lnw = (const float*)d_in[10];
  const float* lnb = (const float*)d_in[11];
  float* out = (float*)d_out;

  // layout ordered so every depth-1 prefetch overrun lands in a following buffer
  // (Q last: it is never prefetch-read)
  char* ws = (char*)d_ws;
  __bf16* Wb  = (__bf16*)(ws + 9437184);     //   393,216 B
  __bf16* Wob = (__bf16*)(ws + 9830400);     //   131,072 B
  __bf16* Kd  = (__bf16*)(ws + 9961472);     // 4,718,592 B
  __bf16* Vt  = (__bf16*)(ws + 14680064);    // 4,718,592 B
  __bf16* att = (__bf16*)(ws + 19398656);    // 4,718,592 B
  __bf16* Q   = (__bf16*)(ws + 24117248);    // 4,718,592 B

  k_cvtw <<< 256, 256, 0, stream>>>(Wq, Wk, Wv, Wo, Wb, Wob);
  k_qkv  <<< 864, 256, 0, stream>>>(x, ctx, Wb, bq, bk, bv, Q, Kd, Vt);
  k_attn <<<1152, 256, 0, stream>>>(Q, Kd, Vt, att);
  k_oln  <<< 576, 256, 0, stream>>>(att, Wob, bo, x, lnw, lnb, out);
}